// Round 6
// baseline (93.010 us; speedup 1.0000x reference)
//
#include <hip/hip_runtime.h>

#define HD 64      // HIDDEN_DIM
#define VC 128     // VOCAB_SIZE
#define NS 64      // NUM_SLOTS
#define NB 256     // B
#define SL 4096    // L

typedef __attribute__((ext_vector_type(8))) short short8;
typedef __attribute__((ext_vector_type(4))) float f32x4;

// swizzled ushort index into a [row][128] bf16 tile (row stride 256B).
// XOR of bits 3-5 (16B granules) by row&7 spreads stride-256B column accesses
// across 8 distinct 16B slots -> bank-conflict-floor reads AND writes.
#define SWZ(row, col_u) ((((row) * VC) + (col_u)) ^ (((row) & 7) << 3))

__device__ __forceinline__ float wsum(float x) {
#pragma unroll
  for (int o = 32; o > 0; o >>= 1) x += __shfl_xor(x, o, 64);
  return x;
}
__device__ __forceinline__ float wmax(float x) {
#pragma unroll
  for (int o = 32; o > 0; o >>= 1) x = fmaxf(x, __shfl_xor(x, o, 64));
  return x;
}

// Kernel 1: per-vocab tables, emitted in k2-ready form:
//   WSMT[n][v] = softmax_n(HN[v] @ gate_w + gate_b)   (f32, transposed)
//   HtHi/HtLo[SWZ(h,v)] = split-bf16 of HN[v][h]      (pre-swizzled blob)
// ALL weight loads are issued in ONE register burst at kernel entry (the
// 256 MiB inter-iteration fills evict L2/L3, so every load is cold ~900cy;
// the old structure paid that latency once per phase, serially).
__global__ __launch_bounds__(128) void build_tables(
    const float* __restrict__ embed, const float* __restrict__ w1, const float* __restrict__ b1,
    const float* __restrict__ w2, const float* __restrict__ b2,
    const float* __restrict__ ln_g, const float* __restrict__ ln_b,
    const float* __restrict__ gate_w, const float* __restrict__ gate_b,
    float* __restrict__ WSMT, unsigned short* __restrict__ HtHi,
    unsigned short* __restrict__ HtLo)
{
  const int v = blockIdx.x, t = threadIdx.x;
  const int col = t & 63;        // output column for ff2/gate phases
  const int half = t >> 6;       // which half of the k-range this thread covers
  __shared__ float s_e[HD], s_f1[2 * HD], s_hn[HD], s_red[128];

  // ---- One burst: every global this block will ever read ----
  if (t < HD) s_e[t] = embed[v * HD + t];

  float w1c[64];                 // w1[h][t], column t
#pragma unroll
  for (int h = 0; h < 64; ++h) w1c[h] = w1[h * 2 * HD + t];

  float w2c[64];                 // w2[half*64 + j][col]
#pragma unroll
  for (int j = 0; j < 64; ++j) w2c[j] = w2[(half * 64 + j) * HD + col];

  float gwc[32];                 // gate_w[half*32 + h][col]
#pragma unroll
  for (int h = 0; h < 32; ++h) gwc[h] = gate_w[(half * 32 + h) * NS + col];

  const float b1t = b1[t];
  const float b2c = b2[col];
  const float lgc = ln_g[col];
  const float lbc = ln_b[col];
  const float gbc = gate_b[col];
  __syncthreads();               // s_e ready (weight loads keep flying)

  // ff1 = relu(e @ w1 + b1), one output per thread (128 outputs)
  {
    float a0 = 0.f, a1 = 0.f, a2 = 0.f, a3 = 0.f;
#pragma unroll
    for (int h = 0; h < HD; h += 4) {
      a0 = fmaf(s_e[h + 0], w1c[h + 0], a0);
      a1 = fmaf(s_e[h + 1], w1c[h + 1], a1);
      a2 = fmaf(s_e[h + 2], w1c[h + 2], a2);
      a3 = fmaf(s_e[h + 3], w1c[h + 3], a3);
    }
    s_f1[t] = fmaxf(b1t + ((a0 + a1) + (a2 + a3)), 0.f);
  }
  __syncthreads();

  // ff2 partial: j-range [64*half, 64*half+64) for output `col`
  {
    const int j0 = half << 6;
    float a0 = 0.f, a1 = 0.f, a2 = 0.f, a3 = 0.f;
#pragma unroll
    for (int j = 0; j < 64; j += 4) {
      a0 = fmaf(s_f1[j0 + j + 0], w2c[j + 0], a0);
      a1 = fmaf(s_f1[j0 + j + 1], w2c[j + 1], a1);
      a2 = fmaf(s_f1[j0 + j + 2], w2c[j + 2], a2);
      a3 = fmaf(s_f1[j0 + j + 3], w2c[j + 3], a3);
    }
    s_red[t] = (a0 + a1) + (a2 + a3);
  }
  __syncthreads();

  // residual + layernorm (wave 0); emit split-bf16 Ht directly
  if (t < HD) {
    float x = s_e[t] + b2c + s_red[t] + s_red[t + 64];
    float mu = wsum(x) * (1.f / 64.f);
    float d = x - mu;
    float var = wsum(d * d) * (1.f / 64.f);
    float hn = d * rsqrtf(var + 1e-5f) * lgc + lbc;
    s_hn[t] = hn;
    const unsigned int hb_ = __float_as_uint(hn);
    const unsigned short hi = (unsigned short)(hb_ >> 16);
    const float rem = hn - __uint_as_float(hb_ & 0xffff0000u);
    const unsigned short lo = (unsigned short)(__float_as_uint(rem) >> 16);
    const int idx = SWZ(t, v);
    HtHi[idx] = hi;
    HtLo[idx] = lo;
  }
  __syncthreads();

  // gate logit partial: h-range [32*half, 32*half+32) for output `col`
  {
    const int hh0 = half << 5;
    float a0 = 0.f, a1 = 0.f, a2 = 0.f, a3 = 0.f;
#pragma unroll
    for (int h = 0; h < 32; h += 4) {
      a0 = fmaf(s_hn[hh0 + h + 0], gwc[h + 0], a0);
      a1 = fmaf(s_hn[hh0 + h + 1], gwc[h + 1], a1);
      a2 = fmaf(s_hn[hh0 + h + 2], gwc[h + 2], a2);
      a3 = fmaf(s_hn[hh0 + h + 3], gwc[h + 3], a3);
    }
    s_red[t] = (a0 + a1) + (a2 + a3);
  }
  __syncthreads();

  // gate softmax over slots (wave 0); store transposed
  if (t < NS) {
    float g = gbc + s_red[t] + s_red[t + 64];
    float m = wmax(g);
    float e = expf(g - m);
    float s = wsum(e);
    WSMT[t * VC + v] = e / s;
  }
}

// Kernel 2: UNCHANGED from round 5 (verified; further micro-opt proven null).
__global__ __launch_bounds__(1024) void batch_kernel(
    const int* __restrict__ seq, const float* __restrict__ WSMT,
    const unsigned short* __restrict__ HtHi, const unsigned short* __restrict__ HtLo,
    const float* __restrict__ slot_keys, const float* __restrict__ out_w,
    const float* __restrict__ out_b, float* __restrict__ out)
{
  const int b = blockIdx.x, t = threadIdx.x;
  const int lane = t & 63, wave = t >> 6;

  __shared__ int s_cnt[VC];
  __shared__ int s_qtok;
  __align__(16) __shared__ unsigned short s_wt_hi[NS * VC];  // 16 KB: A hi, swizzled
  __align__(16) __shared__ unsigned short s_wt_lo[NS * VC];  // 16 KB: A lo
  __align__(16) __shared__ unsigned short s_ht_hi[HD * VC];  // 16 KB: B^T hi (blob copy)
  __align__(16) __shared__ unsigned short s_ht_lo[HD * VC];  // 16 KB: B^T lo
  __align__(16) __shared__ float s_ow[HD * VC];              // 32 KB: out_w
  __align__(16) __shared__ float s_keys[NS * HD];            // 16 KB
  __align__(16) __shared__ float s_part[16 * HD];            // 4 KB
  __shared__ float s_q[HD], s_sim[NS], s_ctx[HD];

  // W staging map: thread -> (slot row wn, vocab octet wv8); coalesced global read.
  const int wn = t >> 4;
  const int wv8 = (t & 15) << 3;

  // MFMA tile assignment: wave -> 16x16 output tile; lane -> fragment coords.
  const int n0 = (wave & 3) << 4;
  const int h0 = (wave >> 2) << 4;
  const int fr = lane & 15;   // frag row (A) / col (B) / D col
  const int fg = lane >> 4;   // k-group

  // ---- Prologue: issue ALL global loads at once (one HBM latency total) ----
  const int4 sv = ((const int4*)(seq + b * SL))[t];           // tokens 4t..4t+3
  const float4 wt0 = *(const float4*)&WSMT[wn * VC + wv8];    // W^T row chunk
  const float4 wt1 = *(const float4*)&WSMT[wn * VC + wv8 + 4];
  const short8 hhi = ((const short8*)HtHi)[t];                // Ht blobs, linear
  const short8 hlo = ((const short8*)HtLo)[t];
  const float4 ow0 = ((const float4*)out_w)[t];               // out_w, linear
  const float4 ow1 = ((const float4*)out_w)[t + 1024];
  const float ob = (t < VC) ? out_b[t] : 0.f;
  float skv[4];
#pragma unroll
  for (int r = 0; r < 4; ++r)
    skv[r] = slot_keys[(n0 + fg * 4 + r) * HD + h0 + fr];     // mfma C-init

  if (t < VC) s_cnt[t] = 0;
  __syncthreads();

  // ---- Phase 1: histogram + cnt-independent LDS staging (Ht, out_w) ----
  atomicAdd(&s_cnt[sv.x], 1);
  atomicAdd(&s_cnt[sv.y], 1);
  atomicAdd(&s_cnt[sv.z], 1);
  if (t != 1023) atomicAdd(&s_cnt[sv.w], 1);
  else s_qtok = sv.w;                            // seq[b, L-1] excluded
  ((short8*)s_ht_hi)[t] = hhi;
  ((short8*)s_ht_lo)[t] = hlo;
  ((float4*)s_ow)[t] = ow0;
  ((float4*)s_ow)[t + 1024] = ow1;
  __syncthreads();                               // cnt + qtok + Ht + ow ready

  // ---- Phase 2: cnt-scale W^T, split-bf16, swizzled stage; reconstruct q ----
  {
    const int4 c0 = *(const int4*)&s_cnt[wv8];
    const int4 c1 = *(const int4*)&s_cnt[wv8 + 4];
    float wf[8] = {wt0.x, wt0.y, wt0.z, wt0.w, wt1.x, wt1.y, wt1.z, wt1.w};
    const int cc[8] = {c0.x, c0.y, c0.z, c0.w, c1.x, c1.y, c1.z, c1.w};
    short8 vhi, vlo;
#pragma unroll
    for (int j = 0; j < 8; ++j) {
      const float w = wf[j] * (float)cc[j];
      const unsigned int wb_ = __float_as_uint(w);
      vhi[j] = (short)(wb_ >> 16);
      const float wr = w - __uint_as_float(wb_ & 0xffff0000u);
      vlo[j] = (short)(__float_as_uint(wr) >> 16);
    }
    const int idx = SWZ(wn, wv8);                // 16B-aligned
    *(short8*)&s_wt_hi[idx] = vhi;
    *(short8*)&s_wt_lo[idx] = vlo;
  }
  if (t < HD) {
    const int qtok = s_qtok;
    const unsigned int hi = s_ht_hi[SWZ(t, qtok)];
    const unsigned int lo = s_ht_lo[SWZ(t, qtok)];
    s_q[t] = __uint_as_float(hi << 16) + __uint_as_float(lo << 16);
  }
  __syncthreads();                               // Wt staged

  // ---- Phase 3: MFMA GEMM, full k=128 per wave (round-4 verified layout) ----
  {
    f32x4 acc = {skv[0], skv[1], skv[2], skv[3]};
#pragma unroll
    for (int kc = 0; kc < 4; ++kc) {
      const int au = SWZ(n0 + fr, fg * 8 + kc * 32);
      const int bu = SWZ(h0 + fr, fg * 8 + kc * 32);
      const short8 ahi = *(const short8*)&s_wt_hi[au];
      const short8 alo = *(const short8*)&s_wt_lo[au];
      const short8 bhi = *(const short8*)&s_ht_hi[bu];
      const short8 blo = *(const short8*)&s_ht_lo[bu];
      acc = __builtin_amdgcn_mfma_f32_16x16x32_bf16(ahi, bhi, acc, 0, 0, 0);
      acc = __builtin_amdgcn_mfma_f32_16x16x32_bf16(ahi, blo, acc, 0, 0, 0);
      acc = __builtin_amdgcn_mfma_f32_16x16x32_bf16(alo, bhi, acc, 0, 0, 0);
      acc = __builtin_amdgcn_mfma_f32_16x16x32_bf16(alo, blo, acc, 0, 0, 0);
    }
    // D layout: col = lane&15 (h), row = (lane>>4)*4 + r (n)  [m89-verified]
#pragma unroll
    for (int r = 0; r < 4; ++r)
      s_keys[(n0 + fg * 4 + r) * HD + h0 + fr] = acc[r];
  }
  __syncthreads();

  // ---- Phase 4: sim[n] — each of 16 waves owns 4 slot rows ----
  const float qv = s_q[lane];
  const float qn = fmaxf(sqrtf(wsum(qv * qv)), 1e-12f);
#pragma unroll
  for (int r = 0; r < 4; ++r) {
    const int n = (wave << 2) + r;
    const float kv = s_keys[n * HD + lane];
    const float kk = wsum(kv * kv);
    const float kq = wsum(kv * qv);
    if (lane == 0) s_sim[n] = kq / (fmaxf(sqrtf(kk), 1e-12f) * qn);
  }
  __syncthreads();

  // ---- Phase 5+6 fused: redundant in-register softmax + ctx partials ----
  {
    const float svv = s_sim[lane];
    const float m = wmax(svv);
    const float e = expf(svv - m);
    const float ssum = wsum(e);
    const float attn_l = e / ssum;
    float c = 0.f;
#pragma unroll
    for (int r = 0; r < 4; ++r) {
      const int n = (wave << 2) + r;
      const float an = __shfl(attn_l, n, 64);
      c = fmaf(an, s_keys[n * HD + lane], c);
    }
    s_part[wave * HD + lane] = c;
  }
  __syncthreads();
  if (wave == 0) {
    float c0 = 0.f, c1 = 0.f, c2 = 0.f, c3 = 0.f;
#pragma unroll
    for (int w = 0; w < 16; w += 4) {
      c0 += s_part[(w + 0) * HD + lane];
      c1 += s_part[(w + 1) * HD + lane];
      c2 += s_part[(w + 2) * HD + lane];
      c3 += s_part[(w + 3) * HD + lane];
    }
    s_ctx[lane] = (c0 + c1) + (c2 + c3);
  }
  __syncthreads();

  // ---- Phase 7: out = ctx @ out_w + out_b, entirely from LDS ----
  if (t < VC) {
    float o0 = 0.f, o1 = 0.f, o2 = 0.f, o3 = 0.f;
#pragma unroll
    for (int h = 0; h < HD; h += 4) {
      o0 = fmaf(s_ctx[h + 0], s_ow[(h + 0) * VC + t], o0);
      o1 = fmaf(s_ctx[h + 1], s_ow[(h + 1) * VC + t], o1);
      o2 = fmaf(s_ctx[h + 2], s_ow[(h + 2) * VC + t], o2);
      o3 = fmaf(s_ctx[h + 3], s_ow[(h + 3) * VC + t], o3);
    }
    out[b * VC + t] = ob + ((o0 + o1) + (o2 + o3));
  }
}

extern "C" void kernel_launch(void* const* d_in, const int* in_sizes, int n_in,
                              void* d_out, int out_size, void* d_ws, size_t ws_size,
                              hipStream_t stream) {
  const int* seq         = (const int*)d_in[0];
  const float* embed_w   = (const float*)d_in[1];
  const float* w1        = (const float*)d_in[2];
  const float* b1        = (const float*)d_in[3];
  const float* w2        = (const float*)d_in[4];
  const float* b2        = (const float*)d_in[5];
  const float* ln_g      = (const float*)d_in[6];
  const float* ln_b      = (const float*)d_in[7];
  const float* slot_keys = (const float*)d_in[8];
  // d_in[9] = slot_vals: unused (reference sets vals = keys)
  const float* gate_w    = (const float*)d_in[10];
  const float* gate_b    = (const float*)d_in[11];
  const float* out_w     = (const float*)d_in[12];
  const float* out_b     = (const float*)d_in[13];
  float* out = (float*)d_out;

  float* WSMT = (float*)d_ws;                       // 64*128 f32 (32 KB)
  unsigned short* HtHi = (unsigned short*)(WSMT + NS * VC);  // 16 KB blob
  unsigned short* HtLo = HtHi + HD * VC;                     // 16 KB blob

  build_tables<<<VC, 128, 0, stream>>>(embed_w, w1, b1, w2, b2, ln_g, ln_b,
                                       gate_w, gate_b, WSMT, HtHi, HtLo);
  batch_kernel<<<NB, 1024, 0, stream>>>(seq, WSMT, HtHi, HtLo, slot_keys,
                                        out_w, out_b, out);
}